// Round 12
// baseline (89.646 us; speedup 1.0000x reference)
//
#include <hip/hip_runtime.h>

// CharacterCNN — ABLATION ROUND. prep + 4 cnn variants launched in order:
//   MODE 3 (floor: masks + store), MODE 2 (noGEMM: phase1 + store),
//   MODE 1 (noP1: cheap cnn fill + full GEMM pipeline), MODE 0 (FULL, last
//   so d_out is correct). Per-dispatch rocprof rows give the decomposition.

typedef _Float16 f16;
typedef __attribute__((ext_vector_type(8))) _Float16 f16x8;
typedef __attribute__((ext_vector_type(4))) float f32x4;

typedef const unsigned int __attribute__((address_space(1)))* gas_t;
typedef unsigned int __attribute__((address_space(3)))* las_t;

#define LC1   0
#define LRAW2 96
#define LT2   672
#define LRAW3 1696
#define LT3LO 5152
#define LT3HI 7200
#define WOFFB 18944
#define PBASE 100352
#define NWTH  114688
#define WSPLIT_BLOCKS 448
#define LUT_BLOCKS 4
#define CROW 232

#define VM4 asm volatile("s_waitcnt vmcnt(4)" ::: "memory")
#define VM3 asm volatile("s_waitcnt vmcnt(3)" ::: "memory")
#define VM0 asm volatile("s_waitcnt vmcnt(0)" ::: "memory")
#define SBAR __builtin_amdgcn_sched_barrier(0)
#define BARR __builtin_amdgcn_s_barrier()

__device__ __forceinline__ f16x8 hmax8(f16x8 a, f16x8 b) {
  return __builtin_elementwise_max(a, b);
}

__device__ __forceinline__ f16x8 pin8(f16x8 v) {
  union { f16x8 v; unsigned w[4]; } x; x.v = v;
  asm volatile("" : "+v"(x.w[0]), "+v"(x.w[1]), "+v"(x.w[2]), "+v"(x.w[3]) :: "memory");
  return x.v;
}

__device__ __forceinline__ void stage_chunk(const f16* __restrict__ src,
                                            f16* dst, int wave, int lane) {
  const char* s = (const char*)src + lane * 16;
  char* d = (char*)dst;
#pragma unroll
  for (int r = 0; r < 3; r++) {
    int j = wave + r * 4;
    __builtin_amdgcn_global_load_lds((gas_t)(s + j * 1024),
                                     (las_t)(d + j * 1024), 16, 0, 0);
  }
  if (wave < 2) {
    int j = wave + 12;
    __builtin_amdgcn_global_load_lds((gas_t)(s + j * 1024),
                                     (las_t)(d + j * 1024), 16, 0, 0);
  }
}

// ---------------- prep kernel (unchanged) ----------------
__global__ __launch_bounds__(256) void prep_kernel(
    const float* __restrict__ E,
    const float* __restrict__ W1, const float* __restrict__ b1,
    const float* __restrict__ W2, const float* __restrict__ b2,
    const float* __restrict__ W3, const float* __restrict__ b3,
    const float* __restrict__ HtW, const float* __restrict__ HgW,
    const float* __restrict__ PW,
    f16* __restrict__ tab, f16* __restrict__ wsb)
{
  const int tid = threadIdx.x;
  if (blockIdx.x < WSPLIT_BLOCKS) {
    int idx = blockIdx.x * 256 + tid;
    if (idx < NWTH) {
      int e, isG = 0, isP = 0;
      if (idx < 50176)        { e = idx; }
      else if (idx < 100352)  { e = idx - 50176; isG = 1; }
      else                    { e = idx - 100352; isP = 1; }
      int col = e / 224, k = e - col * 224;
      int nf = col >> 4, kf = k >> 5, kr = k & 31;
      int lane = (col & 15) + ((kr >> 3) << 4), j = kr & 7;
      if (!isP) {
        int off = nf * 7168 + (isG * 7 + kf) * 512 + lane * 8 + j;
        wsb[off] = (f16)(isG ? HgW[e] : HtW[e]);
      } else {
        float w = PW[e];
        f16 hi = (f16)w;
        int off = PBASE + nf * 7168 + kf * 512 + lane * 8 + j;
        wsb[off] = hi;
        wsb[off + 3584] = (f16)(w - (float)hi);
      }
    }
    return;
  }

  __shared__ float X[3][16];
  __shared__ float U1[3][32];
  __shared__ float U2[9][64];
  __shared__ float U3[27][128];
  const int gid = (blockIdx.x - WSPLIT_BLOCKS) * 256 + tid;
  const int gsz = LUT_BLOCKS * 256;
  if (tid < 48) { int s = tid >> 4, i = tid & 15; X[s][i] = (s == 0) ? 0.f : E[(s - 1) * 16 + i]; }
  __syncthreads();

  for (int idx = tid; idx < 96; idx += 256) {
    int s = idx >> 5, c = idx & 31;
    float acc = b1[c];
#pragma unroll
    for (int i = 0; i < 16; i++) acc += W1[c * 16 + i] * X[s][i];
    U1[s][c] = acc;
  }
  for (int idx = tid; idx < 576; idx += 256) {
    int p = idx >> 6, c = idx & 63;
    int sa = p / 3, sb = p % 3;
    float acc = b2[c];
#pragma unroll
    for (int i = 0; i < 16; i++)
      acc += W2[c * 32 + i * 2 + 0] * X[sa][i] + W2[c * 32 + i * 2 + 1] * X[sb][i];
    U2[p][c] = acc;
  }
  for (int idx = tid; idx < 3456; idx += 256) {
    int p = idx >> 7, c = idx & 127;
    int sa = p / 9, sb = (p / 3) % 3, sc = p % 3;
    float acc = b3[c];
#pragma unroll
    for (int i = 0; i < 16; i++)
      acc += W3[c * 48 + i * 3 + 0] * X[sa][i]
           + W3[c * 48 + i * 3 + 1] * X[sb][i]
           + W3[c * 48 + i * 3 + 2] * X[sc][i];
    U3[p][c] = acc;
  }
  __syncthreads();

  for (int idx = gid; idx < 96; idx += gsz) {
    int r = idx >> 5, c = idx & 31;
    float v = (r == 0) ? fmaxf(U1[1][c], U1[2][c]) : U1[r][c];
    tab[LC1 + idx] = (f16)v;
  }
  for (int idx = gid; idx < 576; idx += gsz) tab[LRAW2 + idx] = (f16)U2[idx >> 6][idx & 63];
  for (int idx = gid; idx < 3456; idx += gsz) tab[LRAW3 + idx] = (f16)U3[idx >> 7][idx & 127];
  for (int idx = gid; idx < 1024; idx += gsz) {
    int s = idx >> 6, c = idx & 63;
    float m = -65504.f;
#pragma unroll
    for (int b = 0; b < 4; b++)
      if ((s >> b) & 1) m = fmaxf(m, U2[4 + 3 * (b >> 1) + (b & 1)][c]);
    tab[LT2 + idx] = (f16)m;
  }
  for (int idx = gid; idx < 2048; idx += gsz) {
    int s = idx >> 7, c = idx & 127;
    float m = -65504.f;
#pragma unroll
    for (int b = 0; b < 4; b++)
      if ((s >> b) & 1) m = fmaxf(m, U3[13 + 3 * (b >> 1) + (b & 1)][c]);
    tab[LT3LO + idx] = (f16)m;
    m = -65504.f;
#pragma unroll
    for (int b = 0; b < 4; b++)
      if ((s >> b) & 1) m = fmaxf(m, U3[22 + 3 * (b >> 1) + (b & 1)][c]);
    tab[LT3HI + idx] = (f16)m;
  }
}

// ------------- cnn kernel, 4 ablation modes -------------
// MODE 0: full.  MODE 1: GEMM only (cheap cnn fill).  MODE 2: phase1 only.
// MODE 3: masks + store floor.
template<int MODE>
__global__ __launch_bounds__(256) void cnn_kernel(
    const int* __restrict__ ids,
    const f16* __restrict__ tab, const f16* __restrict__ wsb,
    const float* __restrict__ Htb, const float* __restrict__ Hgb,
    const float* __restrict__ Pb,
    float* __restrict__ out, int n_tok)
{
  __shared__ __attribute__((aligned(16))) f16 cnn[64 * CROW];
  __shared__ __attribute__((aligned(16))) f16 wbufA[7168];
  __shared__ __attribute__((aligned(16))) f16 wbufB[7168];
  __shared__ unsigned masks[64][2];

  const int tid = threadIdx.x;
  const int wave = tid >> 6, lane = tid & 63;
  const int tok0 = blockIdx.x * 64;
  const int rbase = wave * 16;
  const int lrow = lane & 15;
  const int kg8 = (lane >> 4) * 8;
  const int rr0 = (lane >> 4) * 4;

  // equal LDS footprint in all modes
  if (MODE >= 2) { cnn[tid] = (f16)0; wbufA[tid] = (f16)0; wbufB[tid] = (f16)0; }

  float btv[14], bgv[14], bpv[4];
  if (MODE <= 1) {
#pragma unroll
    for (int nf = 0; nf < 14; nf++) {
      btv[nf] = Htb[nf * 16 + lrow];
      bgv[nf] = Hgb[nf * 16 + lrow];
    }
#pragma unroll
    for (int nf = 0; nf < 4; nf++) bpv[nf] = Pb[nf * 16 + lrow];
  }

  // ---- masks (all modes) ----
  if (lane < 16) {
    int row = rbase + lane;
    unsigned mw = 0, mb = 0;
    if (tok0 + row < n_tok) {
      const int4* idp4 = (const int4*)(ids + (size_t)(tok0 + row) * 20);
      int st[22]; st[0] = 0; st[21] = 0;
#pragma unroll
      for (int q = 0; q < 5; q++) {
        int4 v = idp4[q];
        st[q * 4 + 1] = v.x + 1; st[q * 4 + 2] = v.y + 1;
        st[q * 4 + 3] = v.z + 1; st[q * 4 + 4] = v.w + 1;
      }
      unsigned m3i = 0, m2i = 0, mchar = 0;
#pragma unroll
      for (int l = 1; l <= 18; l++) m3i |= 1u << ((st[l] - 1) * 4 + (st[l + 1] - 1) * 2 + (st[l + 2] - 1));
#pragma unroll
      for (int l = 1; l <= 19; l++) m2i |= 1u << ((st[l] - 1) * 2 + (st[l + 1] - 1));
#pragma unroll
      for (int l = 1; l <= 20; l++) mchar |= 1u << (st[l] - 1);
      int sel = (mchar == 3u) ? 0 : ((mchar & 1u) ? 1 : 2);
      mw = m3i | (m2i << 8) | ((unsigned)sel << 12);
      mb = (unsigned)st[1] | ((unsigned)(st[20] * 3) << 4)
         | ((unsigned)(st[1] * 3 + st[2]) << 8) | ((unsigned)(st[19] * 9 + st[20] * 3) << 16);
    }
    masks[row][0] = mw; masks[row][1] = mb;
  }

  if (MODE == 3) {   // floor: consume masks, write full out footprint
    unsigned mw = masks[rbase + lrow][0] ^ masks[rbase + lrow][1];
    float sv = (float)(mw & 0xFFFFu);
#pragma unroll
    for (int c4 = 0; c4 < 4; c4++)
#pragma unroll
      for (int r = 0; r < 4; r++) {
        int row = rbase + rr0 + r;
        if (tok0 + row < n_tok) out[(size_t)(tok0 + row) * 64 + c4 * 16 + lrow] = sv;
      }
    return;
  }

  // ---- phase 1 ----
  const f16x8 KZ = {0, 0, 0, 0, 0, 0, 0, 0};
  if (MODE == 1) {   // cheap deterministic fill, masks-derived, finite
    const int tl = lane >> 2, q = lane & 3;
    const int row = rbase + tl;
    unsigned short base = (unsigned short)((masks[row][0] ^ masks[row][1]) & 0x3BFF);
    union { unsigned short u[8]; f16x8 v; } fv;
#pragma unroll
    for (int j = 0; j < 8; j++) fv.u[j] = (unsigned short)(base + j);
#pragma unroll
    for (int seg = 0; seg < 7; seg++)
      *(f16x8*)&cnn[row * CROW + seg * 32 + q * 8] = fv.v;
  } else {           // MODES 0,2: real gather
    const int tl = lane >> 2, q = lane & 3;
    const int row = rbase + tl;
    const unsigned mw = masks[row][0], mb = masks[row][1];
    const int sel = (mw >> 12) & 3;
    {
      f16x8 v = *(const f16x8*)(tab + LC1 + sel * 32 + q * 8);
      *(f16x8*)&cnn[row * CROW + q * 8] = hmax8(v, KZ);
    }
#pragma unroll
    for (int jj = 0; jj < 2; jj++) {
      int g = q + jj * 4;
      f16x8 v = *(const f16x8*)(tab + LT2 + ((mw >> 8) & 15) * 64 + g * 8);
      v = hmax8(v, *(const f16x8*)(tab + LRAW2 + (mb & 15) * 64 + g * 8));
      v = hmax8(v, *(const f16x8*)(tab + LRAW2 + ((mb >> 4) & 15) * 64 + g * 8));
      *(f16x8*)&cnn[row * CROW + 32 + g * 8] = hmax8(v, KZ);
    }
    const int m3 = mw & 255;
#pragma unroll
    for (int jj = 0; jj < 4; jj++) {
      int g = q + jj * 4;
      f16x8 v = hmax8(*(const f16x8*)(tab + LT3LO + (m3 & 15) * 128 + g * 8),
                      *(const f16x8*)(tab + LT3HI + ((m3 >> 4) & 15) * 128 + g * 8));
      v = hmax8(v, *(const f16x8*)(tab + LRAW3 + ((mb >> 8) & 15) * 128 + g * 8));
      v = hmax8(v, *(const f16x8*)(tab + LRAW3 + ((mb >> 16) & 31) * 128 + g * 8));
      *(f16x8*)&cnn[row * CROW + 96 + g * 8] = hmax8(v, KZ);
    }
  }

  // ---- A-fragments ----
  f16x8 af[7];
#pragma unroll
  for (int kf = 0; kf < 7; kf++)
    af[kf] = *(const f16x8*)&cnn[(rbase + lrow) * CROW + kf * 32 + kg8];
#pragma unroll
  for (int kf = 0; kf < 7; kf++) af[kf] = pin8(af[kf]);

  if (MODE == 2) {   // phase1-only: consume af, write full out footprint
    unsigned acc = 0;
#pragma unroll
    for (int kf = 0; kf < 7; kf++) {
      union { f16x8 v; unsigned u[4]; } x; x.v = af[kf];
      acc ^= x.u[0] ^ x.u[1] ^ x.u[2] ^ x.u[3];
    }
    float sv = (float)(acc & 0xFFFFu);
#pragma unroll
    for (int c4 = 0; c4 < 4; c4++)
#pragma unroll
      for (int r = 0; r < 4; r++) {
        int row = rbase + rr0 + r;
        if (tok0 + row < n_tok) out[(size_t)(tok0 + row) * 64 + c4 * 16 + lrow] = sv;
      }
    return;
  }

  // ---- 18-chunk pipeline (MODES 0,1) ----
  f16x8 ah[7];
  stage_chunk(wsb, wbufA, wave, lane);
#pragma unroll
  for (int ci = 0; ci < 18; ci++) {
    f16* cur = (ci & 1) ? wbufB : wbufA;
    f16* nxt = (ci & 1) ? wbufA : wbufB;
    if (ci + 1 < 18) {
      const f16* src = (ci + 1 < 14) ? (wsb + (ci + 1) * 7168)
                                     : (wsb + PBASE + (ci + 1 - 14) * 7168);
      stage_chunk(src, nxt, wave, lane);
      if (wave < 2) { VM4; } else { VM3; }
    } else {
      VM0;
    }
    SBAR; BARR; SBAR;

    if (ci < 14) {
      const int col = ci * 16 + lrow;
      const float bt = btv[ci], bg = bgv[ci];
      f32x4 aT = {bt, bt, bt, bt};
      f32x4 aG = {bg, bg, bg, bg};
#pragma unroll
      for (int kf = 0; kf < 7; kf++) {
        f16x8 wTv = *(const f16x8*)&cur[kf * 512 + lane * 8];
        f16x8 wGv = *(const f16x8*)&cur[(7 + kf) * 512 + lane * 8];
        aT = __builtin_amdgcn_mfma_f32_16x16x32_f16(af[kf], wTv, aT, 0, 0, 0);
        aG = __builtin_amdgcn_mfma_f32_16x16x32_f16(af[kf], wGv, aG, 0, 0, 0);
      }
#pragma unroll
      for (int r = 0; r < 4; r++) {
        int row = rbase + rr0 + r;
        float t  = fmaxf(aT[r], 0.f);
        float gg = __builtin_amdgcn_rcpf(1.f + __expf(-aG[r]));
        float cv = (float)cnn[row * CROW + col];
        cnn[row * CROW + col] = (f16)(cv + gg * (t - cv));
      }
    } else {
      if (ci == 14) {
#pragma unroll
        for (int kf = 0; kf < 7; kf++)
          ah[kf] = *(const f16x8*)&cnn[(rbase + lrow) * CROW + kf * 32 + kg8];
      }
      const int pc = ci - 14;
      const int col = pc * 16 + lrow;
      const float bp = bpv[pc];
      f32x4 ac = {bp, bp, bp, bp};
#pragma unroll
      for (int kf = 0; kf < 7; kf++) {
        f16x8 wh = *(const f16x8*)&cur[kf * 512 + lane * 8];
        f16x8 wl = *(const f16x8*)&cur[3584 + kf * 512 + lane * 8];
        ac = __builtin_amdgcn_mfma_f32_16x16x32_f16(ah[kf], wh, ac, 0, 0, 0);
        ac = __builtin_amdgcn_mfma_f32_16x16x32_f16(ah[kf], wl, ac, 0, 0, 0);
      }
#pragma unroll
      for (int r = 0; r < 4; r++) {
        int row = rbase + rr0 + r;
        if (tok0 + row < n_tok) out[(size_t)(tok0 + row) * 64 + col] = ac[r];
      }
    }
    asm volatile("" ::: "memory");
    BARR; SBAR;
  }
}

extern "C" void kernel_launch(void* const* d_in, const int* in_sizes, int n_in,
                              void* d_out, int out_size, void* d_ws, size_t ws_size,
                              hipStream_t stream) {
  const int*   ids = (const int*)d_in[0];
  const float* E   = (const float*)d_in[1];
  const float* W1  = (const float*)d_in[2];
  const float* b1  = (const float*)d_in[3];
  const float* W2  = (const float*)d_in[4];
  const float* b2  = (const float*)d_in[5];
  const float* W3  = (const float*)d_in[6];
  const float* b3  = (const float*)d_in[7];
  const float* HtW = (const float*)d_in[8];
  const float* Htb = (const float*)d_in[9];
  const float* HgW = (const float*)d_in[10];
  const float* Hgb = (const float*)d_in[11];
  const float* PW  = (const float*)d_in[12];
  const float* Pb  = (const float*)d_in[13];
  float* out = (float*)d_out;
  f16* tab = (f16*)d_ws;
  f16* wsb = (f16*)((char*)d_ws + WOFFB);

  const int n_tok = in_sizes[0] / 20;
  const int nblk = (n_tok + 63) / 64;
  prep_kernel<<<WSPLIT_BLOCKS + LUT_BLOCKS, 256, 0, stream>>>(
      E, W1, b1, W2, b2, W3, b3, HtW, HgW, PW, tab, wsb);
  cnn_kernel<3><<<nblk, 256, 0, stream>>>(ids, tab, wsb, Htb, Hgb, Pb, out, n_tok);
  cnn_kernel<2><<<nblk, 256, 0, stream>>>(ids, tab, wsb, Htb, Hgb, Pb, out, n_tok);
  cnn_kernel<1><<<nblk, 256, 0, stream>>>(ids, tab, wsb, Htb, Hgb, Pb, out, n_tok);
  cnn_kernel<0><<<nblk, 256, 0, stream>>>(ids, tab, wsb, Htb, Hgb, Pb, out, n_tok);
}

// Round 14
// 44.951 us; speedup vs baseline: 1.9943x; 1.9943x over previous
//
#include <hip/hip_runtime.h>

// CharacterCNN — DEDUPE-BY-12-BIT-KEY. out[token] is a pure function of
// key = (m3i:8 | st1:1 | st2:1 | st19:1 | st20:1). m2i/mchar/sel are
// derivable from m3i (+boundary): trigram windows cover all 20 positions.
// Pipeline: prep (wsplit+luts+clear) -> key -> compact -> ucompute(<=4096
// unique) -> scatter. Fallback: monolithic compute<0> if ws too small.

typedef _Float16 f16;
typedef __attribute__((ext_vector_type(8))) _Float16 f16x8;
typedef __attribute__((ext_vector_type(4))) float f32x4;

// ---- table element offsets (f16 units) ----
#define LC1   0
#define LRAW2 96
#define LT2   672
#define LRAW3 1696
#define LT3LO 5152
#define LT3HI 7200
// ---- ws byte layout ----
#define WOFFB    18944      // f16 weights: 129,024 f16 = 258,048 B -> ends 276,992
#define PBASE    100352     // f16-unit offset of P chunks inside wsb
#define NWTH     114688
#define CNT_OFF  278528     // u32 counter          (past weight end 276,992)
#define FLAG_OFF 278784     // u8[4096]
#define SMAP_OFF 282880     // u32[4096]
#define UKEY_OFF 299264     // u32[4096]
#define TKEY_OFF 315648     // u32[65536]
#define UOUT_OFF 577792     // f32[4096*64] -> ends 1,626,368
#define TOTAL_NEED 1626368
#define NKEYS    4096
#define CLRN     1088       // dwords: [CNT_OFF, FLAG_OFF+4096)
#define WSPLIT_BLOCKS 448
#define LUT_BLOCKS 4
#define CLR_BLOCKS 5
#define CROW 232

__device__ __forceinline__ f16x8 hmax8(f16x8 a, f16x8 b) {
  return __builtin_elementwise_max(a, b);
}

__device__ __forceinline__ f16x8 pin8(f16x8 v) {
  union { f16x8 v; unsigned w[4]; } x; x.v = v;
  asm volatile("" : "+v"(x.w[0]), "+v"(x.w[1]), "+v"(x.w[2]), "+v"(x.w[3]) :: "memory");
  return x.v;
}

// ---------------- prep kernel: wsplit + luts + clear ----------------
__global__ __launch_bounds__(256) void prep_kernel(
    const float* __restrict__ E,
    const float* __restrict__ W1, const float* __restrict__ b1,
    const float* __restrict__ W2, const float* __restrict__ b2,
    const float* __restrict__ W3, const float* __restrict__ b3,
    const float* __restrict__ HtW, const float* __restrict__ HgW,
    const float* __restrict__ PW,
    f16* __restrict__ tab, f16* __restrict__ wsb,
    unsigned* __restrict__ clrbase, int do_clear)
{
  const int tid = threadIdx.x;
  if (blockIdx.x >= WSPLIT_BLOCKS + LUT_BLOCKS) {       // clear cnt+flags
    if (do_clear) {
      int idx = (blockIdx.x - WSPLIT_BLOCKS - LUT_BLOCKS) * 256 + tid;
      if (idx < CLRN) clrbase[idx] = 0;
    }
    return;
  }
  if (blockIdx.x < WSPLIT_BLOCKS) {
    int idx = blockIdx.x * 256 + tid;
    if (idx < NWTH) {
      int e, isG = 0, isP = 0;
      if (idx < 50176)        { e = idx; }
      else if (idx < 100352)  { e = idx - 50176; isG = 1; }
      else                    { e = idx - 100352; isP = 1; }
      int col = e / 224, k = e - col * 224;
      int nf = col >> 4, kf = k >> 5, kr = k & 31;
      int lane = (col & 15) + ((kr >> 3) << 4), j = kr & 7;
      if (!isP) {
        int off = nf * 7168 + (isG * 7 + kf) * 512 + lane * 8 + j;
        wsb[off] = (f16)(isG ? HgW[e] : HtW[e]);
      } else {
        float w = PW[e];
        f16 hi = (f16)w;
        int off = PBASE + nf * 7168 + kf * 512 + lane * 8 + j;
        wsb[off] = hi;
        wsb[off + 3584] = (f16)(w - (float)hi);
      }
    }
    return;
  }

  // ---- LUT part ----
  __shared__ float X[3][16];
  __shared__ float U1[3][32];
  __shared__ float U2[9][64];
  __shared__ float U3[27][128];
  const int gid = (blockIdx.x - WSPLIT_BLOCKS) * 256 + tid;
  const int gsz = LUT_BLOCKS * 256;
  if (tid < 48) { int s = tid >> 4, i = tid & 15; X[s][i] = (s == 0) ? 0.f : E[(s - 1) * 16 + i]; }
  __syncthreads();

  for (int idx = tid; idx < 96; idx += 256) {
    int s = idx >> 5, c = idx & 31;
    float acc = b1[c];
#pragma unroll
    for (int i = 0; i < 16; i++) acc += W1[c * 16 + i] * X[s][i];
    U1[s][c] = acc;
  }
  for (int idx = tid; idx < 576; idx += 256) {
    int p = idx >> 6, c = idx & 63;
    int sa = p / 3, sb = p % 3;
    float acc = b2[c];
#pragma unroll
    for (int i = 0; i < 16; i++)
      acc += W2[c * 32 + i * 2 + 0] * X[sa][i] + W2[c * 32 + i * 2 + 1] * X[sb][i];
    U2[p][c] = acc;
  }
  for (int idx = tid; idx < 3456; idx += 256) {
    int p = idx >> 7, c = idx & 127;
    int sa = p / 9, sb = (p / 3) % 3, sc = p % 3;
    float acc = b3[c];
#pragma unroll
    for (int i = 0; i < 16; i++)
      acc += W3[c * 48 + i * 3 + 0] * X[sa][i]
           + W3[c * 48 + i * 3 + 1] * X[sb][i]
           + W3[c * 48 + i * 3 + 2] * X[sc][i];
    U3[p][c] = acc;
  }
  __syncthreads();

  for (int idx = gid; idx < 96; idx += gsz) {
    int r = idx >> 5, c = idx & 31;
    float v = (r == 0) ? fmaxf(U1[1][c], U1[2][c]) : U1[r][c];
    tab[LC1 + idx] = (f16)v;
  }
  for (int idx = gid; idx < 576; idx += gsz) tab[LRAW2 + idx] = (f16)U2[idx >> 6][idx & 63];
  for (int idx = gid; idx < 3456; idx += gsz) tab[LRAW3 + idx] = (f16)U3[idx >> 7][idx & 127];
  for (int idx = gid; idx < 1024; idx += gsz) {
    int s = idx >> 6, c = idx & 63;
    float m = -65504.f;
#pragma unroll
    for (int b = 0; b < 4; b++)
      if ((s >> b) & 1) m = fmaxf(m, U2[4 + 3 * (b >> 1) + (b & 1)][c]);
    tab[LT2 + idx] = (f16)m;
  }
  for (int idx = gid; idx < 2048; idx += gsz) {
    int s = idx >> 7, c = idx & 127;
    float m = -65504.f;
#pragma unroll
    for (int b = 0; b < 4; b++)
      if ((s >> b) & 1) m = fmaxf(m, U3[13 + 3 * (b >> 1) + (b & 1)][c]);
    tab[LT3LO + idx] = (f16)m;
    m = -65504.f;
#pragma unroll
    for (int b = 0; b < 4; b++)
      if ((s >> b) & 1) m = fmaxf(m, U3[22 + 3 * (b >> 1) + (b & 1)][c]);
    tab[LT3HI + idx] = (f16)m;
  }
}

// ---------------- key kernel: 12-bit key per token ----------------
__global__ __launch_bounds__(256) void key_kernel(
    const int* __restrict__ ids, unsigned* __restrict__ tokkey,
    unsigned char* __restrict__ flags, int n_tok)
{
  int t = blockIdx.x * 256 + threadIdx.x;
  if (t >= n_tok) return;
  const int4* idp4 = (const int4*)(ids + (size_t)t * 20);
  int st[21];
#pragma unroll
  for (int q = 0; q < 5; q++) {
    int4 v = idp4[q];
    st[q * 4 + 1] = v.x; st[q * 4 + 2] = v.y;   // raw 0/1 here
    st[q * 4 + 3] = v.z; st[q * 4 + 4] = v.w;
  }
  unsigned m3i = 0;
#pragma unroll
  for (int l = 1; l <= 18; l++)
    m3i |= 1u << ((st[l] << 2) | (st[l + 1] << 1) | st[l + 2]);
  unsigned key = m3i | ((unsigned)st[1] << 8) | ((unsigned)st[2] << 9)
               | ((unsigned)st[19] << 10) | ((unsigned)st[20] << 11);
  tokkey[t] = key;
  flags[key] = 1;
}

// ---------------- compact kernel ----------------
__global__ __launch_bounds__(256) void compact_kernel(
    const unsigned char* __restrict__ flags, unsigned* __restrict__ cnt,
    unsigned* __restrict__ smap, unsigned* __restrict__ ukey)
{
  int k = blockIdx.x * 256 + threadIdx.x;
  if (k < NKEYS && flags[k]) {
    unsigned s = atomicAdd(cnt, 1u);
    smap[k] = s;
    ukey[s] = k;
  }
}

// -------- compute kernel: SRC=1 unique keys -> uout; SRC=0 tokens -> out ----
template<int SRC>
__global__ __launch_bounds__(256) void compute_kernel(
    const int* __restrict__ ids,
    const f16* __restrict__ tab, const f16* __restrict__ wsb,
    const float* __restrict__ Htb, const float* __restrict__ Hgb,
    const float* __restrict__ Pb,
    const unsigned* __restrict__ cnt, const unsigned* __restrict__ ukey,
    float* __restrict__ obuf, int n_tok)
{
  const int nrows = SRC ? (int)*cnt : n_tok;
  const int base = blockIdx.x * 64;
  if (base >= nrows) return;

  __shared__ __attribute__((aligned(16))) f16 cnn[64 * CROW];
  __shared__ unsigned masks[64][2];

  const int tid = threadIdx.x;
  const int wave = tid >> 6, lane = tid & 63;
  const int rbase = wave * 16;
  const int lrow = lane & 15;
  const int kg8 = (lane >> 4) * 8;
  const int rr0 = (lane >> 4) * 4;

  // ---- masks: lanes 0..15 per wave ----
  if (lane < 16) {
    int row = rbase + lane;
    unsigned mw = 0, mb = 0;
    if (base + row < nrows) {
      unsigned m3i;
      int st1, st2, st19, st20;
      if (SRC) {
        unsigned key = ukey[base + row];
        m3i = key & 255u;
        st1 = 1 + (int)((key >> 8) & 1);  st2 = 1 + (int)((key >> 9) & 1);
        st19 = 1 + (int)((key >> 10) & 1); st20 = 1 + (int)((key >> 11) & 1);
      } else {
        const int4* idp4 = (const int4*)(ids + (size_t)(base + row) * 20);
        int st[21];
#pragma unroll
        for (int q = 0; q < 5; q++) {
          int4 v = idp4[q];
          st[q * 4 + 1] = v.x; st[q * 4 + 2] = v.y;
          st[q * 4 + 3] = v.z; st[q * 4 + 4] = v.w;
        }
        m3i = 0;
#pragma unroll
        for (int l = 1; l <= 18; l++)
          m3i |= 1u << ((st[l] << 2) | (st[l + 1] << 1) | st[l + 2]);
        st1 = 1 + st[1]; st2 = 1 + st[2]; st19 = 1 + st[19]; st20 = 1 + st[20];
      }
      // derive m2i (prefix|suffix bigrams) and mchar from m3i
      unsigned m2i = 0, mchar = 0;
#pragma unroll
      for (int p = 0; p < 8; p++)
        if ((m3i >> p) & 1) {
          m2i |= (1u << (p >> 1)) | (1u << (p & 3));
          mchar |= (1u << ((p >> 2) & 1)) | (1u << ((p >> 1) & 1)) | (1u << (p & 1));
        }
      unsigned sel = (mchar == 3u) ? 0u : ((mchar & 1u) ? 1u : 2u);
      mw = m3i | (m2i << 8) | (sel << 12);
      mb = (unsigned)st1 | ((unsigned)(st20 * 3) << 4)
         | ((unsigned)(st1 * 3 + st2) << 8) | ((unsigned)(st19 * 9 + st20 * 3) << 16);
    }
    masks[rbase + lane][0] = mw; masks[rbase + lane][1] = mb;
  }
  // same-wave LDS write->read ordering via lgkmcnt; no barrier needed

  // ---- phase 1: table gather, ReLU clamp ----
  const f16x8 KZ = {0, 0, 0, 0, 0, 0, 0, 0};
  {
    const int tl = lane >> 2, q = lane & 3;
    const int row = rbase + tl;
    const unsigned mw = masks[row][0], mb = masks[row][1];
    const int sel = (mw >> 12) & 3;
    {
      f16x8 v = *(const f16x8*)(tab + LC1 + sel * 32 + q * 8);
      *(f16x8*)&cnn[row * CROW + q * 8] = hmax8(v, KZ);
    }
#pragma unroll
    for (int jj = 0; jj < 2; jj++) {
      int g = q + jj * 4;
      f16x8 v = *(const f16x8*)(tab + LT2 + ((mw >> 8) & 15) * 64 + g * 8);
      v = hmax8(v, *(const f16x8*)(tab + LRAW2 + (mb & 15) * 64 + g * 8));
      v = hmax8(v, *(const f16x8*)(tab + LRAW2 + ((mb >> 4) & 15) * 64 + g * 8));
      *(f16x8*)&cnn[row * CROW + 32 + g * 8] = hmax8(v, KZ);
    }
    const int m3 = mw & 255;
#pragma unroll
    for (int jj = 0; jj < 4; jj++) {
      int g = q + jj * 4;
      f16x8 v = hmax8(*(const f16x8*)(tab + LT3LO + (m3 & 15) * 128 + g * 8),
                      *(const f16x8*)(tab + LT3HI + ((m3 >> 4) & 15) * 128 + g * 8));
      v = hmax8(v, *(const f16x8*)(tab + LRAW3 + ((mb >> 8) & 15) * 128 + g * 8));
      v = hmax8(v, *(const f16x8*)(tab + LRAW3 + ((mb >> 16) & 31) * 128 + g * 8));
      *(f16x8*)&cnn[row * CROW + 96 + g * 8] = hmax8(v, KZ);
    }
  }

  // ---- A-fragments ----
  f16x8 af[7];
#pragma unroll
  for (int kf = 0; kf < 7; kf++)
    af[kf] = *(const f16x8*)&cnn[(rbase + lrow) * CROW + kf * 32 + kg8];
#pragma unroll
  for (int kf = 0; kf < 7; kf++) af[kf] = pin8(af[kf]);

  const f16* wbase = wsb + lane * 8;

#define LOADW(NF, T, G)                                                  \
  {                                                                      \
    const f16* p_ = wbase + (NF) * 7168;                                 \
    _Pragma("unroll")                                                    \
    for (int kf = 0; kf < 7; kf++) {                                     \
      T[kf] = *(const f16x8*)(p_ + kf * 512);                            \
      G[kf] = *(const f16x8*)(p_ + 3584 + kf * 512);                     \
    }                                                                    \
  }

#define HWY(NF, T, G)                                                    \
  {                                                                      \
    const int col = (NF) * 16 + lrow;                                    \
    const float bt = Htb[col], bg = Hgb[col];                            \
    f32x4 aT = {bt, bt, bt, bt};                                         \
    f32x4 aG = {bg, bg, bg, bg};                                         \
    _Pragma("unroll")                                                    \
    for (int kf = 0; kf < 7; kf++) {                                     \
      aT = __builtin_amdgcn_mfma_f32_16x16x32_f16(af[kf], T[kf], aT, 0, 0, 0); \
      aG = __builtin_amdgcn_mfma_f32_16x16x32_f16(af[kf], G[kf], aG, 0, 0, 0); \
    }                                                                    \
    _Pragma("unroll")                                                    \
    for (int r = 0; r < 4; r++) {                                        \
      int row = rbase + rr0 + r;                                         \
      float t = fmaxf(aT[r], 0.f);                                       \
      float gg = __builtin_amdgcn_rcpf(1.f + __expf(-aG[r]));            \
      float cv = (float)cnn[row * CROW + col];                           \
      cnn[row * CROW + col] = (f16)(cv + gg * (t - cv));                 \
    }                                                                    \
  }

  {
    f16x8 TA[7], GA[7], TB[7], GB[7];
    LOADW(0, TA, GA);
#pragma unroll
    for (int nf = 0; nf < 14; nf += 2) {
      LOADW(nf + 1, TB, GB);
      HWY(nf, TA, GA);
      if (nf + 2 < 14) LOADW(nf + 2, TA, GA);
      HWY(nf + 1, TB, GB);
    }
  }

  // ---- projection (hi+lo) ----
  f16x8 ah[7];
#pragma unroll
  for (int kf = 0; kf < 7; kf++)
    ah[kf] = *(const f16x8*)&cnn[(rbase + lrow) * CROW + kf * 32 + kg8];

#pragma unroll 2
  for (int nf = 0; nf < 4; nf++) {
    const int col = nf * 16 + lrow;
    const float bp = Pb[col];
    f32x4 ac = {bp, bp, bp, bp};
    const f16* ph = wbase + PBASE + nf * 7168;
#pragma unroll
    for (int kf = 0; kf < 7; kf++) {
      f16x8 wh = *(const f16x8*)(ph + kf * 512);
      f16x8 wl = *(const f16x8*)(ph + 3584 + kf * 512);
      ac = __builtin_amdgcn_mfma_f32_16x16x32_f16(ah[kf], wh, ac, 0, 0, 0);
      ac = __builtin_amdgcn_mfma_f32_16x16x32_f16(ah[kf], wl, ac, 0, 0, 0);
    }
#pragma unroll
    for (int r = 0; r < 4; r++) {
      int row = base + rbase + rr0 + r;
      if (row < nrows) obuf[(size_t)row * 64 + col] = ac[r];
    }
  }
#undef LOADW
#undef HWY
}

// ---------------- scatter kernel ----------------
__global__ __launch_bounds__(256) void scatter_kernel(
    const unsigned* __restrict__ tokkey, const unsigned* __restrict__ smap,
    const float* __restrict__ uout, float* __restrict__ out, int n_tok)
{
  int gid = blockIdx.x * 256 + threadIdx.x;
  int t = gid >> 2, q = gid & 3;
  if (t >= n_tok) return;
  unsigned s = smap[tokkey[t]];
  const float4* src = (const float4*)(uout + (size_t)s * 64 + q * 16);
  float4* dst = (float4*)(out + (size_t)t * 64 + q * 16);
  dst[0] = src[0]; dst[1] = src[1]; dst[2] = src[2]; dst[3] = src[3];
}

extern "C" void kernel_launch(void* const* d_in, const int* in_sizes, int n_in,
                              void* d_out, int out_size, void* d_ws, size_t ws_size,
                              hipStream_t stream) {
  const int*   ids = (const int*)d_in[0];
  const float* E   = (const float*)d_in[1];
  const float* W1  = (const float*)d_in[2];
  const float* b1  = (const float*)d_in[3];
  const float* W2  = (const float*)d_in[4];
  const float* b2  = (const float*)d_in[5];
  const float* W3  = (const float*)d_in[6];
  const float* b3  = (const float*)d_in[7];
  const float* HtW = (const float*)d_in[8];
  const float* Htb = (const float*)d_in[9];
  const float* HgW = (const float*)d_in[10];
  const float* Hgb = (const float*)d_in[11];
  const float* PW  = (const float*)d_in[12];
  const float* Pb  = (const float*)d_in[13];
  float* out = (float*)d_out;
  char* ws = (char*)d_ws;
  f16* tab = (f16*)ws;
  f16* wsb = (f16*)(ws + WOFFB);
  unsigned* cnt = (unsigned*)(ws + CNT_OFF);
  unsigned char* flags = (unsigned char*)(ws + FLAG_OFF);
  unsigned* smap = (unsigned*)(ws + SMAP_OFF);
  unsigned* tokkey = (unsigned*)(ws + TKEY_OFF);
  unsigned* ukey = (unsigned*)(ws + UKEY_OFF);
  float* uout = (float*)(ws + UOUT_OFF);

  const int n_tok = in_sizes[0] / 20;
  const bool dedup = ws_size >= (size_t)TOTAL_NEED && n_tok <= 65536;

  prep_kernel<<<WSPLIT_BLOCKS + LUT_BLOCKS + CLR_BLOCKS, 256, 0, stream>>>(
      E, W1, b1, W2, b2, W3, b3, HtW, HgW, PW, tab, wsb, cnt, dedup ? 1 : 0);
  if (dedup) {
    key_kernel<<<(n_tok + 255) / 256, 256, 0, stream>>>(ids, tokkey, flags, n_tok);
    compact_kernel<<<NKEYS / 256, 256, 0, stream>>>(flags, cnt, smap, ukey);
    compute_kernel<1><<<NKEYS / 64, 256, 0, stream>>>(
        ids, tab, wsb, Htb, Hgb, Pb, cnt, ukey, uout, n_tok);
    scatter_kernel<<<((size_t)n_tok * 4 + 255) / 256, 256, 0, stream>>>(
        tokkey, smap, uout, out, n_tok);
  } else {
    compute_kernel<0><<<(n_tok + 63) / 64, 256, 0, stream>>>(
        ids, tab, wsb, Htb, Hgb, Pb, cnt, ukey, out, n_tok);
  }
}

// Round 15
// 31.899 us; speedup vs baseline: 2.8103x; 1.4092x over previous
//
#include <hip/hip_runtime.h>

// CharacterCNN — DEDUPE-BY-12-BIT-KEY, direct-indexed (no compaction).
// out[token] = F(key), key = m3i:8 | st1:1 | st2:1 | st19:1 | st20:1.
// uout[4096][64] indexed by key directly; ALL 4096 rows computed (256
// blocks x 16 keys, 1 block/CU -> wall = one shallow block latency).
// Pipeline (3 launches): [prep+key] -> [ucompute] -> [scatter].

typedef _Float16 f16;
typedef __attribute__((ext_vector_type(8))) _Float16 f16x8;
typedef __attribute__((ext_vector_type(4))) float f32x4;

// ---- table element offsets (f16 units) ----
#define LC1   0
#define LRAW2 96
#define LT2   672
#define LRAW3 1696
#define LT3LO 5152
#define LT3HI 7200
// ---- ws byte layout ----
#define WOFFB    18944      // f16 weights: 129,024 f16 = 258,048 B -> ends 276,992
#define PBASE    100352     // f16-unit offset of P chunks inside wsb
#define NWTH     114688
#define TKEY_OFF 278528     // u32[65536] -> ends 540,672
#define UOUT_OFF 544768     // f32[4096*64] -> ends 1,593,344
#define NKEYS    4096
#define WSPLIT_BLOCKS 448
#define LUT_BLOCKS 4
#define CROW 232

__device__ __forceinline__ f16x8 hmax8(f16x8 a, f16x8 b) {
  return __builtin_elementwise_max(a, b);
}

__device__ __forceinline__ f16x8 pin8(f16x8 v) {
  union { f16x8 v; unsigned w[4]; } x; x.v = v;
  asm volatile("" : "+v"(x.w[0]), "+v"(x.w[1]), "+v"(x.w[2]), "+v"(x.w[3]) :: "memory");
  return x.v;
}

// ---------------- kernel 1: prep (wsplit + luts) + key extraction ----------------
__global__ __launch_bounds__(256) void prep_key_kernel(
    const float* __restrict__ E,
    const float* __restrict__ W1, const float* __restrict__ b1,
    const float* __restrict__ W2, const float* __restrict__ b2,
    const float* __restrict__ W3, const float* __restrict__ b3,
    const float* __restrict__ HtW, const float* __restrict__ HgW,
    const float* __restrict__ PW, const int* __restrict__ ids,
    f16* __restrict__ tab, f16* __restrict__ wsb,
    unsigned* __restrict__ tokkey, int n_tok)
{
  const int tid = threadIdx.x;
  if (blockIdx.x >= WSPLIT_BLOCKS + LUT_BLOCKS) {       // ---- key blocks ----
    int t = (blockIdx.x - WSPLIT_BLOCKS - LUT_BLOCKS) * 256 + tid;
    if (t >= n_tok) return;
    const int4* idp4 = (const int4*)(ids + (size_t)t * 20);
    int st[21];
#pragma unroll
    for (int q = 0; q < 5; q++) {
      int4 v = idp4[q];
      st[q * 4 + 1] = v.x; st[q * 4 + 2] = v.y;   // raw 0/1
      st[q * 4 + 3] = v.z; st[q * 4 + 4] = v.w;
    }
    unsigned m3i = 0;
#pragma unroll
    for (int l = 1; l <= 18; l++)
      m3i |= 1u << ((st[l] << 2) | (st[l + 1] << 1) | st[l + 2]);
    tokkey[t] = m3i | ((unsigned)st[1] << 8) | ((unsigned)st[2] << 9)
              | ((unsigned)st[19] << 10) | ((unsigned)st[20] << 11);
    return;
  }
  if (blockIdx.x < WSPLIT_BLOCKS) {                     // ---- weight split ----
    int idx = blockIdx.x * 256 + tid;
    if (idx < NWTH) {
      int e, isG = 0, isP = 0;
      if (idx < 50176)        { e = idx; }
      else if (idx < 100352)  { e = idx - 50176; isG = 1; }
      else                    { e = idx - 100352; isP = 1; }
      int col = e / 224, k = e - col * 224;
      int nf = col >> 4, kf = k >> 5, kr = k & 31;
      int lane = (col & 15) + ((kr >> 3) << 4), j = kr & 7;
      if (!isP) {
        int off = nf * 7168 + (isG * 7 + kf) * 512 + lane * 8 + j;
        wsb[off] = (f16)(isG ? HgW[e] : HtW[e]);
      } else {
        float w = PW[e];
        f16 hi = (f16)w;
        int off = PBASE + nf * 7168 + kf * 512 + lane * 8 + j;
        wsb[off] = hi;
        wsb[off + 3584] = (f16)(w - (float)hi);
      }
    }
    return;
  }

  // ---- LUT blocks ----
  __shared__ float X[3][16];
  __shared__ float U1[3][32];
  __shared__ float U2[9][64];
  __shared__ float U3[27][128];
  const int gid = (blockIdx.x - WSPLIT_BLOCKS) * 256 + tid;
  const int gsz = LUT_BLOCKS * 256;
  if (tid < 48) { int s = tid >> 4, i = tid & 15; X[s][i] = (s == 0) ? 0.f : E[(s - 1) * 16 + i]; }
  __syncthreads();

  for (int idx = tid; idx < 96; idx += 256) {
    int s = idx >> 5, c = idx & 31;
    float acc = b1[c];
#pragma unroll
    for (int i = 0; i < 16; i++) acc += W1[c * 16 + i] * X[s][i];
    U1[s][c] = acc;
  }
  for (int idx = tid; idx < 576; idx += 256) {
    int p = idx >> 6, c = idx & 63;
    int sa = p / 3, sb = p % 3;
    float acc = b2[c];
#pragma unroll
    for (int i = 0; i < 16; i++)
      acc += W2[c * 32 + i * 2 + 0] * X[sa][i] + W2[c * 32 + i * 2 + 1] * X[sb][i];
    U2[p][c] = acc;
  }
  for (int idx = tid; idx < 3456; idx += 256) {
    int p = idx >> 7, c = idx & 127;
    int sa = p / 9, sb = (p / 3) % 3, sc = p % 3;
    float acc = b3[c];
#pragma unroll
    for (int i = 0; i < 16; i++)
      acc += W3[c * 48 + i * 3 + 0] * X[sa][i]
           + W3[c * 48 + i * 3 + 1] * X[sb][i]
           + W3[c * 48 + i * 3 + 2] * X[sc][i];
    U3[p][c] = acc;
  }
  __syncthreads();

  for (int idx = gid; idx < 96; idx += gsz) {
    int r = idx >> 5, c = idx & 31;
    float v = (r == 0) ? fmaxf(U1[1][c], U1[2][c]) : U1[r][c];
    tab[LC1 + idx] = (f16)v;
  }
  for (int idx = gid; idx < 576; idx += gsz) tab[LRAW2 + idx] = (f16)U2[idx >> 6][idx & 63];
  for (int idx = gid; idx < 3456; idx += gsz) tab[LRAW3 + idx] = (f16)U3[idx >> 7][idx & 127];
  for (int idx = gid; idx < 1024; idx += gsz) {
    int s = idx >> 6, c = idx & 63;
    float m = -65504.f;
#pragma unroll
    for (int b = 0; b < 4; b++)
      if ((s >> b) & 1) m = fmaxf(m, U2[4 + 3 * (b >> 1) + (b & 1)][c]);
    tab[LT2 + idx] = (f16)m;
  }
  for (int idx = gid; idx < 2048; idx += gsz) {
    int s = idx >> 7, c = idx & 127;
    float m = -65504.f;
#pragma unroll
    for (int b = 0; b < 4; b++)
      if ((s >> b) & 1) m = fmaxf(m, U3[13 + 3 * (b >> 1) + (b & 1)][c]);
    tab[LT3LO + idx] = (f16)m;
    m = -65504.f;
#pragma unroll
    for (int b = 0; b < 4; b++)
      if ((s >> b) & 1) m = fmaxf(m, U3[22 + 3 * (b >> 1) + (b & 1)][c]);
    tab[LT3HI + idx] = (f16)m;
  }
}

// ---------------- kernel 2: ucompute — 16 keys/block, 4 waves split nf ----------------
__global__ __launch_bounds__(256) void ucompute_kernel(
    const f16* __restrict__ tab, const f16* __restrict__ wsb,
    const float* __restrict__ Htb, const float* __restrict__ Hgb,
    const float* __restrict__ Pb, float* __restrict__ uout)
{
  __shared__ __attribute__((aligned(16))) f16 cnn[16 * CROW];

  const int tid = threadIdx.x;
  const int wave = tid >> 6, lane = tid & 63;
  const int kbase = blockIdx.x * 16;
  const int lrow = lane & 15;
  const int kg8 = (lane >> 4) * 8;
  const int rr0 = (lane >> 4) * 4;

  // ---- masks derived per-thread from this thread's phase-1 row ----
  const int p1row = tid >> 4;           // 16 rows, 16 threads each
  const int p1g = tid & 15;             // col-group
  unsigned mw, mb;
  {
    unsigned key = (unsigned)(kbase + p1row);
    unsigned m3i = key & 255u;
    int st1 = 1 + (int)((key >> 8) & 1),  st2 = 1 + (int)((key >> 9) & 1);
    int st19 = 1 + (int)((key >> 10) & 1), st20 = 1 + (int)((key >> 11) & 1);
    unsigned m2i = 0, mchar = 0;
#pragma unroll
    for (int p = 0; p < 8; p++)
      if ((m3i >> p) & 1) {
        m2i |= (1u << (p >> 1)) | (1u << (p & 3));
        mchar |= (1u << ((p >> 2) & 1)) | (1u << ((p >> 1) & 1)) | (1u << (p & 1));
      }
    unsigned sel = (mchar == 3u) ? 0u : ((mchar & 1u) ? 1u : 2u);
    mw = m3i | (m2i << 8) | (sel << 12);
    mb = (unsigned)st1 | ((unsigned)(st20 * 3) << 4)
       | ((unsigned)(st1 * 3 + st2) << 8) | ((unsigned)(st19 * 9 + st20 * 3) << 16);
  }

  // ---- phase 1: all 256 threads; thread fills conv3[g], conv2[g<8], conv1[g<4] ----
  const f16x8 KZ = {0, 0, 0, 0, 0, 0, 0, 0};
  {
    const int m3 = mw & 255;
    f16x8 v = hmax8(*(const f16x8*)(tab + LT3LO + (m3 & 15) * 128 + p1g * 8),
                    *(const f16x8*)(tab + LT3HI + ((m3 >> 4) & 15) * 128 + p1g * 8));
    v = hmax8(v, *(const f16x8*)(tab + LRAW3 + ((mb >> 8) & 15) * 128 + p1g * 8));
    v = hmax8(v, *(const f16x8*)(tab + LRAW3 + ((mb >> 16) & 31) * 128 + p1g * 8));
    *(f16x8*)&cnn[p1row * CROW + 96 + p1g * 8] = hmax8(v, KZ);
    if (p1g < 8) {
      f16x8 u = *(const f16x8*)(tab + LT2 + ((mw >> 8) & 15) * 64 + p1g * 8);
      u = hmax8(u, *(const f16x8*)(tab + LRAW2 + (mb & 15) * 64 + p1g * 8));
      u = hmax8(u, *(const f16x8*)(tab + LRAW2 + ((mb >> 4) & 15) * 64 + p1g * 8));
      *(f16x8*)&cnn[p1row * CROW + 32 + p1g * 8] = hmax8(u, KZ);
    }
    if (p1g < 4) {
      int sel = (mw >> 12) & 3;
      f16x8 w = *(const f16x8*)(tab + LC1 + sel * 32 + p1g * 8);
      *(f16x8*)&cnn[p1row * CROW + p1g * 8] = hmax8(w, KZ);
    }
  }
  __syncthreads();

  // ---- A-fragments: every wave loads all 16 rows' K ----
  f16x8 af[7];
#pragma unroll
  for (int kf = 0; kf < 7; kf++)
    af[kf] = *(const f16x8*)&cnn[lrow * CROW + kf * 32 + kg8];
#pragma unroll
  for (int kf = 0; kf < 7; kf++) af[kf] = pin8(af[kf]);
  __syncthreads();   // all waves captured af before in-place hw writes

  // ---- highway: wave w handles nf = w, w+4, w+8, w+12(w<2); cols disjoint ----
  const f16* wbase = wsb + lane * 8;
  const int nf_cnt = (wave < 2) ? 4 : 3;
  for (int i = 0; i < nf_cnt; i++) {
    const int nf = wave + i * 4;
    const int col = nf * 16 + lrow;
    const f16* p_ = wbase + nf * 7168;
    const float bt = Htb[col], bg = Hgb[col];
    f32x4 aT = {bt, bt, bt, bt};
    f32x4 aG = {bg, bg, bg, bg};
#pragma unroll
    for (int kf = 0; kf < 7; kf++) {
      f16x8 wTv = *(const f16x8*)(p_ + kf * 512);
      f16x8 wGv = *(const f16x8*)(p_ + 3584 + kf * 512);
      aT = __builtin_amdgcn_mfma_f32_16x16x32_f16(af[kf], wTv, aT, 0, 0, 0);
      aG = __builtin_amdgcn_mfma_f32_16x16x32_f16(af[kf], wGv, aG, 0, 0, 0);
    }
#pragma unroll
    for (int r = 0; r < 4; r++) {
      int row = rr0 + r;
      float t  = fmaxf(aT[r], 0.f);
      float gg = __builtin_amdgcn_rcpf(1.f + __expf(-aG[r]));
      float cv = (float)cnn[row * CROW + col];
      cnn[row * CROW + col] = (f16)(cv + gg * (t - cv));
    }
  }
  __syncthreads();   // hw complete before projection reads all cols

  // ---- projection: wave w handles nf = w (P hi+lo) ----
  f16x8 ah[7];
#pragma unroll
  for (int kf = 0; kf < 7; kf++)
    ah[kf] = *(const f16x8*)&cnn[lrow * CROW + kf * 32 + kg8];
  {
    const int col = wave * 16 + lrow;
    const float bp = Pb[col];
    f32x4 ac = {bp, bp, bp, bp};
    const f16* ph = wbase + PBASE + wave * 7168;
#pragma unroll
    for (int kf = 0; kf < 7; kf++) {
      f16x8 wh = *(const f16x8*)(ph + kf * 512);
      f16x8 wl = *(const f16x8*)(ph + 3584 + kf * 512);
      ac = __builtin_amdgcn_mfma_f32_16x16x32_f16(ah[kf], wh, ac, 0, 0, 0);
      ac = __builtin_amdgcn_mfma_f32_16x16x32_f16(ah[kf], wl, ac, 0, 0, 0);
    }
#pragma unroll
    for (int r = 0; r < 4; r++)
      uout[(size_t)(kbase + rr0 + r) * 64 + col] = ac[r];
  }
}

// ---------------- kernel 3: scatter ----------------
__global__ __launch_bounds__(256) void scatter_kernel(
    const unsigned* __restrict__ tokkey, const float* __restrict__ uout,
    float* __restrict__ out, int n_tok)
{
  int gid = blockIdx.x * 256 + threadIdx.x;
  int t = gid >> 2, q = gid & 3;
  if (t >= n_tok) return;
  unsigned s = tokkey[t];
  const float4* src = (const float4*)(uout + (size_t)s * 64 + q * 16);
  float4* dst = (float4*)(out + (size_t)t * 64 + q * 16);
  dst[0] = src[0]; dst[1] = src[1]; dst[2] = src[2]; dst[3] = src[3];
}

extern "C" void kernel_launch(void* const* d_in, const int* in_sizes, int n_in,
                              void* d_out, int out_size, void* d_ws, size_t ws_size,
                              hipStream_t stream) {
  const int*   ids = (const int*)d_in[0];
  const float* E   = (const float*)d_in[1];
  const float* W1  = (const float*)d_in[2];
  const float* b1  = (const float*)d_in[3];
  const float* W2  = (const float*)d_in[4];
  const float* b2  = (const float*)d_in[5];
  const float* W3  = (const float*)d_in[6];
  const float* b3  = (const float*)d_in[7];
  const float* HtW = (const float*)d_in[8];
  const float* Htb = (const float*)d_in[9];
  const float* HgW = (const float*)d_in[10];
  const float* Hgb = (const float*)d_in[11];
  const float* PW  = (const float*)d_in[12];
  const float* Pb  = (const float*)d_in[13];
  float* out = (float*)d_out;
  char* ws = (char*)d_ws;
  f16* tab = (f16*)ws;
  f16* wsb = (f16*)(ws + WOFFB);
  unsigned* tokkey = (unsigned*)(ws + TKEY_OFF);
  float* uout = (float*)(ws + UOUT_OFF);

  const int n_tok = in_sizes[0] / 20;
  const int key_blocks = (n_tok + 255) / 256;

  prep_key_kernel<<<WSPLIT_BLOCKS + LUT_BLOCKS + key_blocks, 256, 0, stream>>>(
      E, W1, b1, W2, b2, W3, b3, HtW, HgW, PW, ids, tab, wsb, tokkey, n_tok);
  ucompute_kernel<<<NKEYS / 16, 256, 0, stream>>>(tab, wsb, Htb, Hgb, Pb, uout);
  scatter_kernel<<<((size_t)n_tok * 4 + 255) / 256, 256, 0, stream>>>(
      tokkey, uout, out, n_tok);
}